// Round 4
// baseline (393.141 us; speedup 1.0000x reference)
//
#include <hip/hip_runtime.h>
#include <hip/hip_bf16.h>

#define NPTS 150
#define KP   168          // padded K for MFMA; 5 K-steps of 32 cover 0..159
#define NPAR 193
#define OSTR 388

// bf16 transposed activation buffers, element offsets into sT
#define H1T  0            // [11][168]  rows 0..9 = h1^T, row 10 = ones (db2)
#define H2T  1848         // [11][168]  rows 0..9 = h2^T, row 10 = ones (db3)
#define XT   3696         // [5][168]   rows 0..3 = x^T,  row 4  = ones (db1)
#define DZ2T 4536         // [10][168]
#define DZ1T 6216         // [10][168]
#define DLT  7896         // [3][168]
#define TTOT 8400         // = 50 rows x 168
#define NROWS 50

typedef __attribute__((ext_vector_type(8))) short short8;
typedef __attribute__((ext_vector_type(4))) float f32x4;

__constant__ float LRS[6] = {0.001f, 0.01f, 0.05f, 0.1f, 0.5f, 1.0f};

// Round-4 theory: kernelA is LATENCY-bound (r3: f32x2 cut VALUBusy 58->48%
// with NO speedup; block lifetime ~12k cycles for ~500 instrs). hipcc drains
// vmcnt(0) before every s_barrier, so global stores issued before a barrier
// put full HBM store-completion on the critical path 3x per block. Fix:
//  (1) ALL global stores deferred until after the last barrier;
//  (2) zero-fill barrier deleted — only the 18 pad cols per row are zeroed,
//      disjoint from data writes (data cols 0..149 of all 50 rows are fully
//      written by x-fill/ones-fill/activation stores before B2);
//  (3) compute restored to round-1 register-preload form (176-184us > 188).
__global__ __launch_bounds__(192)
__attribute__((amdgpu_waves_per_eu(2, 4)))
void mlp_kernelA(
    const float* __restrict__ W1, const float* __restrict__ b1,
    const float* __restrict__ W2, const float* __restrict__ b2,
    const float* __restrict__ W3, const float* __restrict__ b3,
    const float* __restrict__ G1, const float* __restrict__ G2,
    const float* __restrict__ G3, const float* __restrict__ G4,
    const float* __restrict__ G5, const float* __restrict__ G6,
    const float* __restrict__ dx, const float* __restrict__ fv,
    const int* __restrict__ dy, const int* __restrict__ stepsz,
    float* __restrict__ out, float* __restrict__ slots, int storeMode)
{
    const int m    = blockIdx.x;
    const int t    = threadIdx.x;
    const int lane = t & 63;
    const int w    = t >> 6;

    __shared__ alignas(16) __hip_bfloat16 sT[TTOT];
    __shared__ alignas(16) float sP[200];
    __shared__ float red[8];

    const float lr = LRS[stepsz[m]];

    // ---- SGD update: thread t owns param index t; value stays in a REGISTER
    //      (global store deferred to the end so no barrier drains it) ----
    float pw;
    if      (t < 40)  pw = W1[m*40 + t]        - lr * G1[m*40 + t];
    else if (t < 50)  pw = b1[m*10 + (t-40)]   - lr * G2[m*10 + (t-40)];
    else if (t < 150) pw = W2[m*100 + (t-50)]  - lr * G3[m*100 + (t-50)];
    else if (t < 160) pw = b2[m*10 + (t-150)]  - lr * G4[m*10 + (t-150)];
    else if (t < 190) pw = W3[m*30 + (t-160)]  - lr * G5[m*30 + (t-160)];
    else              pw = b3[m*3 + (t-190)]   - lr * G6[m*3 + (t-190)];
    sP[t] = pw;
    float pw2 = 0.f;
    if (t == 0) {
        pw2 = b3[m*3 + 2] - lr * G6[m*3 + 2];
        sP[192] = pw2;
    }

    // ---- pad-column zero: cols 150..167 of every row. MFMA K-loop covers
    //      k=0..159; A-side (dz/dl) pads must be 0.0 and B-side pads finite.
    //      Disjoint from every data write -> NO barrier needed here. ----
    for (int i = t; i < NROWS*18; i += 192) {
        int r = i / 18, c = i - r*18;
        sT[r*KP + 150 + c] = __float2bfloat16(0.f);
    }
    // ---- ones rows, data cols only (pads handled above) ----
    if (t < 150) {
        __hip_bfloat16 one = __float2bfloat16(1.0f);
        sT[H1T + 10*KP + t] = one;
        sT[H2T + 10*KP + t] = one;
        sT[XT  +  4*KP + t] = one;
    }
    // ---- x^T fill: x^T[f][n] = x[n][f] ----
    for (int i = t; i < 600; i += 192) {
        int n = i >> 2, f = i & 3;
        sT[XT + f*KP + n] = __float2bfloat16(dx[i]);
    }

    // ---- per-thread data point (loaded before B1 so latency overlaps) ----
    const bool act = (t < NPTS);
    const int  nc  = act ? t : 0;
    const f32x4 xv = ((const f32x4*)dx)[nc];
    const int   yv = dy[nc];

    __syncthreads();   // B1: sP ready. No outstanding global stores -> cheap.

    // ---- per-wave preload of wave-uniform params (broadcast LDS reads) ----
    float w2[10][10], bb2[10], w3[3][10], bb3[3], bb1[10];
    #pragma unroll
    for (int g = 0; g < 10; g++) {
        #pragma unroll
        for (int h = 0; h < 10; h++) w2[g][h] = sP[50 + g*10 + h];
        bb2[g] = sP[150 + g];
        bb1[g] = sP[40 + g];
    }
    #pragma unroll
    for (int o = 0; o < 3; o++) {
        #pragma unroll
        for (int g = 0; g < 10; g++) w3[o][g] = sP[160 + o*10 + g];
        bb3[o] = sP[190 + o];
    }
    const f32x4* sP4 = (const f32x4*)sP;   // W1 row j at sP4[j]

    // ================= fused forward + backward-dz: ONE point per thread =====
    float lossacc = 0.f, ssacc = 0.f;
    {
        const int n = t;

        float h1v[10];
        #pragma unroll
        for (int j = 0; j < 10; j++) {
            f32x4 wv = sP4[j];
            float z = bb1[j] + xv.x*wv.x + xv.y*wv.y + xv.z*wv.z + xv.w*wv.w;
            h1v[j] = fmaxf(z, 0.f);
        }
        float h2v[10];
        #pragma unroll
        for (int g = 0; g < 10; g++) {
            float z = bb2[g];
            #pragma unroll
            for (int h = 0; h < 10; h++) z += h1v[h] * w2[g][h];
            h2v[g] = fmaxf(z, 0.f);
        }
        float lg[3];
        #pragma unroll
        for (int o = 0; o < 3; o++) {
            float z = bb3[o];
            #pragma unroll
            for (int g = 0; g < 10; g++) z += h2v[g] * w3[o][g];
            lg[o] = z;
        }
        float mx = fmaxf(lg[0], fmaxf(lg[1], lg[2]));
        float e0 = __expf(lg[0]-mx), e1 = __expf(lg[1]-mx), e2 = __expf(lg[2]-mx);
        float s   = e0 + e1 + e2;
        float inv = 1.f / s;
        float lse = mx + __logf(s);
        float ly  = (yv == 0) ? lg[0] : ((yv == 1) ? lg[1] : lg[2]);
        lossacc = act ? (lse - ly) : 0.f;

        float dl[3];
        dl[0] = (e0*inv - ((yv==0)?1.f:0.f)) * (1.f/150.f);
        dl[1] = (e1*inv - ((yv==1)?1.f:0.f)) * (1.f/150.f);
        dl[2] = (e2*inv - ((yv==2)?1.f:0.f)) * (1.f/150.f);

        float dz2v[10];
        #pragma unroll
        for (int g = 0; g < 10; g++) {
            float d = dl[0]*w3[0][g] + dl[1]*w3[1][g] + dl[2]*w3[2][g];
            dz2v[g] = (h2v[g] > 0.f) ? d : 0.f;
        }
        float dz1v[10];
        #pragma unroll
        for (int h = 0; h < 10; h++) {
            float d = 0.f;
            #pragma unroll
            for (int g = 0; g < 10; g++) d += dz2v[g] * w2[g][h];
            dz1v[h] = (h1v[h] > 0.f) ? d : 0.f;
        }

        if (act) {
            #pragma unroll
            for (int j = 0; j < 10; j++) sT[H1T  + j*KP + n] = __float2bfloat16(h1v[j]);
            #pragma unroll
            for (int g = 0; g < 10; g++) sT[H2T  + g*KP + n] = __float2bfloat16(h2v[g]);
            #pragma unroll
            for (int o = 0; o < 3;  o++) sT[DLT  + o*KP + n] = __float2bfloat16(dl[o]);
            #pragma unroll
            for (int g = 0; g < 10; g++) sT[DZ2T + g*KP + n] = __float2bfloat16(dz2v[g]);
            #pragma unroll
            for (int h = 0; h < 10; h++) sT[DZ1T + h*KP + n] = __float2bfloat16(dz1v[h]);
        }
    }
    __syncthreads();   // B2: sT staged. Outstanding = LDS writes only -> cheap.

    // ================= weight-grad GEMMs via MFMA: one tile per wave =========
    f32x4 acc = {0.f, 0.f, 0.f, 0.f};
    int  offv[4]; bool valid[4];
    {
        const short* sTs = reinterpret_cast<const short*>(sT);
        const int mrow = lane & 15, q = lane >> 4;

        int abase, arows, bbase, bcols, woff, nW, boff;
        if      (w == 0) { abase=DZ2T; arows=10; bbase=H1T; bcols=11; woff=50;  nW=10; boff=150; }
        else if (w == 1) { abase=DZ1T; arows=10; bbase=XT;  bcols=5;  woff=0;   nW=4;  boff=40;  }
        else             { abase=DLT;  arows=3;  bbase=H2T; bcols=11; woff=160; nW=10; boff=190; }

        int ar = (mrow < arows) ? mrow : 0;
        int br = (mrow < bcols) ? mrow : 0;
        #pragma unroll
        for (int kk = 0; kk < 5; kk++) {
            int k0 = kk*32 + q*8;
            short8 a = *(const short8*)(sTs + abase + ar*KP + k0);
            short8 b = *(const short8*)(sTs + bbase + br*KP + k0);
            acc = __builtin_amdgcn_mfma_f32_16x16x32_bf16(a, b, acc, 0, 0, 0);
        }
        #pragma unroll
        for (int r = 0; r < 4; r++) {
            int row = q*4 + r;
            valid[r] = (row < arows) && (mrow < bcols);
            offv[r]  = (mrow < nW) ? (woff + row*nW + mrow) : (boff + row);
            if (valid[r]) ssacc += acc[r]*acc[r];
        }
    }

    // ---- reductions: loss (across all 3 waves), sumsq (per-wave tiles) ----
    #pragma unroll
    for (int off = 32; off > 0; off >>= 1) {
        lossacc += __shfl_down(lossacc, off, 64);
        ssacc   += __shfl_down(ssacc,   off, 64);
    }
    if (lane == 0) { red[w] = lossacc; red[4 + w] = ssacc; }
    __syncthreads();   // B3: LDS-only outstanding -> cheap.

    // ================= ALL global stores, after the final barrier ============
    out[(size_t)m*OSTR + t] = fminf(fmaxf(pw, -10000.f), 10000.f);
    #pragma unroll
    for (int r = 0; r < 4; r++)
        if (valid[r]) out[(size_t)m*OSTR + NPAR + offv[r]] = acc[r]; // raw; C scales
    if (t == 0) {
        out[(size_t)m*OSTR + 192] = fminf(fmaxf(pw2, -10000.f), 10000.f);
        float blockss = red[4] + red[5] + red[6];
        if (storeMode) slots[1 + m] = blockss;
        else           atomicAdd(&slots[1 + (m & 1023)], blockss);
        float loss = (red[0] + red[1] + red[2]) * (1.f/150.f);
        out[(size_t)m*OSTR + 386] = loss;
        float imp = fv[m] - loss;
        imp = fminf(fmaxf(imp, -10000.f), 10000.f);
        out[(size_t)m*OSTR + 387] = imp;
    }
}

// Multi-block reduction slots[1..1+count) -> raw total sumsq into slots[0].
__global__ __launch_bounds__(256) void mlp_kernelB(float* __restrict__ slots, int count)
{
    int idx = blockIdx.x * 256 + threadIdx.x;
    int stride = gridDim.x * 256;
    float v = 0.f;
    for (int i = idx; i < count; i += stride) v += slots[1 + i];
    #pragma unroll
    for (int off = 32; off > 0; off >>= 1) v += __shfl_down(v, off, 64);
    __shared__ float red[4];
    int t = threadIdx.x;
    if ((t & 63) == 0) red[t >> 6] = v;
    __syncthreads();
    if (t == 0) {
        float total = red[0] + red[1] + red[2] + red[3];
        atomicAdd(&slots[0], total);
    }
}

// One block per MLP, coalesced RMW over the 193 grad slots; coef derived
// in-register from the raw total (no second reduction kernel).
__global__ __launch_bounds__(192) void mlp_kernelC(float* __restrict__ out,
                                                   const float* __restrict__ slots)
{
    float total = slots[0];
    float coef = fminf(1.f, 10.f / (sqrtf(total) + 1e-6f));
    size_t base = (size_t)blockIdx.x * OSTR + NPAR;
    int t = threadIdx.x;
    out[base + t] *= coef;
    if (t == 0) out[base + 192] *= coef;
}

extern "C" void kernel_launch(void* const* d_in, const int* in_sizes, int n_in,
                              void* d_out, int out_size, void* d_ws, size_t ws_size,
                              hipStream_t stream) {
    const float* W1 = (const float*)d_in[0];
    const float* b1 = (const float*)d_in[1];
    const float* W2 = (const float*)d_in[2];
    const float* b2 = (const float*)d_in[3];
    const float* W3 = (const float*)d_in[4];
    const float* b3 = (const float*)d_in[5];
    const float* G1 = (const float*)d_in[6];
    const float* G2 = (const float*)d_in[7];
    const float* G3 = (const float*)d_in[8];
    const float* G4 = (const float*)d_in[9];
    const float* G5 = (const float*)d_in[10];
    const float* G6 = (const float*)d_in[11];
    const float* dx = (const float*)d_in[12];
    const float* fv = (const float*)d_in[13];
    const int*   dy = (const int*)d_in[14];
    const int*   st = (const int*)d_in[15];
    float* out   = (float*)d_out;
    float* slots = (float*)d_ws;

    int Bn = in_sizes[0] / 40;
    int storeMode = (ws_size >= (size_t)(Bn + 2) * sizeof(float)) ? 1 : 0;

    if (storeMode) hipMemsetAsync(d_ws, 0, 4, stream);       // just slots[0]
    else           hipMemsetAsync(d_ws, 0, 4100, stream);    // slots[0..1024]
    mlp_kernelA<<<Bn, 192, 0, stream>>>(W1,b1,W2,b2,W3,b3,
                                        G1,G2,G3,G4,G5,G6,
                                        dx,fv,dy,st,out,slots,storeMode);
    mlp_kernelB<<<64, 256, 0, stream>>>(slots, storeMode ? Bn : 1024);
    mlp_kernelC<<<Bn, 192, 0, stream>>>(out, slots);
}